// Round 11
// baseline (166.069 us; speedup 1.0000x reference)
//
#include <hip/hip_runtime.h>
#include <hip/hip_bf16.h>
#include <math.h>

typedef unsigned short u16;
typedef unsigned int u32;
typedef __attribute__((ext_vector_type(8))) short bf16x8;   // 8 bf16 = 4 VGPRs
typedef __attribute__((ext_vector_type(4))) short bf16x4;   // 4 bf16 = 2 VGPRs
typedef __attribute__((ext_vector_type(4))) float f32x4;

#define EMBED 768
#define NHEADS 12
#define HDIM 64
#define NBATCH 2
#define SEQ 2048
#define NTOK 4096
#define QKV_N 2304
#define BHTOT 24        // NBATCH*NHEADS
// Q scale folds softmax's 1/sqrt(d) AND log2(e) so attn can use raw v_exp_f32
#define QSCALE 0.18033688011112042f   // 0.125 * log2(e)

__device__ __forceinline__ u16 f2b(float f) {
    __hip_bfloat16 h = __float2bfloat16(f);
    return __builtin_bit_cast(u16, h);
}
__device__ __forceinline__ u32 pk2(float a, float b) {
    return (u32)f2b(a) | ((u32)f2b(b) << 16);
}
__device__ __forceinline__ f32x4 mfma32(bf16x8 a, bf16x8 b, f32x4 c) {
    return __builtin_amdgcn_mfma_f32_16x16x32_bf16(a, b, c, 0, 0, 0);
}
// K=16 MFMA: B-operand layout == C/D layout -> P feeds PV from registers.
#if __has_builtin(__builtin_amdgcn_mfma_f32_16x16x16_bf16)
__device__ __forceinline__ f32x4 mfma16(bf16x4 a, bf16x4 b, f32x4 c) {
    return __builtin_amdgcn_mfma_f32_16x16x16_bf16(a, b, c, 0, 0, 0);
}
#else
__device__ __forceinline__ f32x4 mfma16(bf16x4 a, bf16x4 b, f32x4 c) {
    return __builtin_amdgcn_mfma_f32_16x16x16bf16_1k(a, b, c, 0, 0, 0);
}
#endif

// guaranteed single-instruction 2^x (never libm)
__device__ __forceinline__ float exp2_hw(float x) {
#if __has_builtin(__builtin_amdgcn_exp2f)
    return __builtin_amdgcn_exp2f(x);
#else
    float r;
    asm("v_exp_f32 %0, %1" : "=v"(r) : "v"(x));
    return r;
#endif
}

// async global->LDS, 16B per lane. LDS dest must be base + lane*16 in lane
// order (HW constraint); our swizzle lives on the GLOBAL address side.
__device__ __forceinline__ void async16(const u16* g, u16* l) {
    __builtin_amdgcn_global_load_lds(
        (const __attribute__((address_space(1))) unsigned int*)g,
        (__attribute__((address_space(3))) unsigned int*)l,
        16, 0, 0);
}

// ---------------------------------------------------------------------------
// fp32 -> bf16 cast for x, w_qkv, w_out
// ---------------------------------------------------------------------------
__global__ __launch_bounds__(256)
void cast_kernel(const float* __restrict__ s0, u16* __restrict__ d0, int n0,
                 const float* __restrict__ s1, u16* __restrict__ d1, int n1,
                 const float* __restrict__ s2, u16* __restrict__ d2, int n2)
{
    int idx = (blockIdx.x * 256 + threadIdx.x) * 4;
    const float* s; u16* d; int i;
    if (idx < n0)            { s = s0; d = d0; i = idx; }
    else if (idx < n0 + n1)  { s = s1; d = d1; i = idx - n0; }
    else                     { s = s2; d = d2; i = idx - n0 - n1; if (i >= n2) return; }
    float4 v = *(const float4*)&s[i];
    ushort4 o;
    o.x = f2b(v.x); o.y = f2b(v.y); o.z = f2b(v.z); o.w = f2b(v.w);
    *(ushort4*)&d[i] = o;
}

// ---------------------------------------------------------------------------
// QKV projection (R10, frozen): 128x128 tile, BK=32, NK=24, counted-vmcnt
// depth-2 pipeline, NBUF=3. T-scratch (36KB) reuses staging LDS.
// ---------------------------------------------------------------------------
__global__ __launch_bounds__(256, 3)
void qkv_gemm(const u16* __restrict__ A, const u16* __restrict__ W,
              const float* __restrict__ bias,
              u16* __restrict__ Qb, u16* __restrict__ Kb, u16* __restrict__ VT)
{
    __shared__ __align__(16) u16 smem[24576];   // 48KB: 3x(As 8KB|Bs 8KB); reused as T (36KB)
    const int m0 = blockIdx.x * 128;
    const int n0 = blockIdx.y * 128;
    const int tid = threadIdx.x;
    const int w = tid >> 6, l = tid & 63;
    const int c = l & 15, q = l >> 4;
    const int wm = (w >> 1) * 64, wn = (w & 1) * 64;
    const int sr = l >> 2;
    const int gch2 = (l & 3) ^ ((l >> 3) & 3);  // (row>>1)&3 involution swizzle
    const int NK = EMBED / 32;   // 24

#define QSTAGE(KT, BS) {                                                      \
    int k0 = (KT) * 32;                                                       \
    _Pragma("unroll")                                                         \
    for (int j = 0; j < 2; ++j) {                                             \
        int row = j * 64 + w * 16 + sr;                                       \
        int seg = (BS) * 8192 + (j * 64 + w * 16) * 32;                       \
        async16(&A[(size_t)(m0 + row) * EMBED + k0 + gch2 * 8],               \
                &smem[seg + l * 8]);                                          \
        async16(&W[(size_t)(n0 + row) * EMBED + k0 + gch2 * 8],               \
                &smem[seg + 4096 + l * 8]);                                   \
    }                                                                         \
}

    f32x4 acc[4][4] = {};

#define QBODY(KT, BC, BS) {                                                   \
    if ((KT) + 1 < NK) asm volatile("s_waitcnt vmcnt(4)" ::: "memory");       \
    else               asm volatile("s_waitcnt vmcnt(0)" ::: "memory");       \
    __builtin_amdgcn_s_barrier();                                             \
    if ((KT) + 2 < NK) QSTAGE((KT) + 2, BS);                                  \
    const u16* Ab = &smem[(BC) * 8192];                                       \
    const u16* Bb = &smem[(BC) * 8192 + 4096];                                \
    const int cs = (q ^ ((c >> 1) & 3)) << 3;                                 \
    bf16x8 af[4], bfr[4];                                                     \
    _Pragma("unroll")                                                         \
    for (int i = 0; i < 4; ++i)                                               \
        af[i] = *(const bf16x8*)&Ab[(wm + i * 16 + c) * 32 + cs];             \
    _Pragma("unroll")                                                         \
    for (int j = 0; j < 4; ++j)                                               \
        bfr[j] = *(const bf16x8*)&Bb[(wn + j * 16 + c) * 32 + cs];            \
    __builtin_amdgcn_s_setprio(1);                                            \
    _Pragma("unroll")                                                         \
    for (int i = 0; i < 4; ++i)                                               \
        _Pragma("unroll")                                                     \
        for (int j = 0; j < 4; ++j)                                           \
            acc[i][j] = mfma32(af[i], bfr[j], acc[i][j]);                     \
    __builtin_amdgcn_s_setprio(0);                                            \
}

    QSTAGE(0, 0);
    QSTAGE(1, 1);

    for (int kt0 = 0; kt0 < NK; kt0 += 3) {
        QBODY(kt0 + 0, 0, 2);
        QBODY(kt0 + 1, 1, 0);
        QBODY(kt0 + 2, 2, 1);
    }
#undef QSTAGE
#undef QBODY

    const int p = n0 / EMBED;                 // 0=q,1=k,2=v (block-uniform)
    const int ncol0 = n0 + wn;
    const int h = (ncol0 % EMBED) / HDIM;
    const int mrow0 = m0 + wm;
    const int b = mrow0 >> 11;
    const int s0 = mrow0 & (SEQ - 1);

    if (p < 2) {
        u16* dst = (p == 0) ? Qb : Kb;
        const float mul = (p == 0) ? QSCALE : 1.0f;
        #pragma unroll
        for (int j = 0; j < 4; ++j) {
            int n = ncol0 + j * 16 + c;
            int d = j * 16 + c;
            float bval = bias[n];
            #pragma unroll
            for (int i = 0; i < 4; ++i) {
                #pragma unroll
                for (int r = 0; r < 4; ++r) {
                    int s = s0 + i * 16 + q * 4 + r;
                    float v = (acc[i][j][r] + bval) * mul;
                    dst[(((size_t)(b * NHEADS + h)) * SEQ + s) * HDIM + d] = f2b(v);
                }
            }
        }
    } else {
        __syncthreads();                      // all MFMA LDS reads done
        u16* T = smem + w * (64 * 72);        // wave-private scratch (36KB < 48KB)
        #pragma unroll
        for (int j = 0; j < 4; ++j) {
            int n = ncol0 + j * 16 + c;
            float bval = bias[n];
            #pragma unroll
            for (int i = 0; i < 4; ++i) {
                uint2 pr;
                pr.x = pk2(acc[i][j][0] + bval, acc[i][j][1] + bval);
                pr.y = pk2(acc[i][j][2] + bval, acc[i][j][3] + bval);
                *(uint2*)&T[(j * 16 + c) * 72 + i * 16 + q * 4] = pr;
            }
        }
        const size_t vtbase = ((size_t)(b * NHEADS + h)) * HDIM * SEQ + s0;
        #pragma unroll
        for (int ii = 0; ii < 8; ++ii) {
            int d = (l >> 3) + 8 * ii;
            int sch = (l & 7) * 8;
            uint4 vv = *(const uint4*)&T[d * 72 + sch];
            *(uint4*)&VT[vtbase + (size_t)d * SEQ + sch] = vv;
        }
    }
}

// ---------------------------------------------------------------------------
// Flash attention R11: TLP restructure with K AND V in LDS (fixing R6's
// mistake of per-body global V loads). Evidence: body time 3547cy vs ~600cy
// of per-wave issue work -> waves idle ~80% on latency; ILP levers (ping-pong,
// depth-2, NBUF3) all null -> raise TLP instead. NBUF 3->2 and q-tile 64->32
// cut LDS 48->32KB => 5 blocks/CU (was 3), grid 1536 (24bh x 64qt),
// launch_bounds(256,5) caps VGPR at 102 (demand ~75, no spill).
// Single-phase body (TLP replaces the S ping-pong): vmcnt(0) [tile J landed,
// staged one full body ago] -> raw barrier [prev body's reads of the other
// buffer are consumed pre-barrier] -> stage J+1 into other buffer ->
// QK^T(J) -> softmax+PV(J). Wave (wq,wk) owns 16 qrows x 32 keys.
// Epilogue: wk-pairs exchange partial O (8KB LDS) + row sums, wk=0 writes AO.
// ---------------------------------------------------------------------------
__global__ __launch_bounds__(256, 5)
void attn_kernel(const u16* __restrict__ Qb, const u16* __restrict__ Kb,
                 const u16* __restrict__ VT, u16* __restrict__ AO)
{
    __shared__ __align__(16) u16 Ks[2][4096];   // 16KB: [buf][64 keys x 64 d] swizzled
    __shared__ __align__(16) u16 Vs[2][4096];   // 16KB: [buf][64 d x 64 keys] swizzled

    const int blk = blockIdx.x;                 // 1536
    const int g = blk & 7, kk = blk >> 3;       // g -> XCD (round-robin heuristic)
    const int bh = g * 3 + (kk >> 6);           // 3 bh per XCD (KV L2 reuse)
    const int qt = kk & 63;                     // 64 q-tiles of 32 rows

    const int tid = threadIdx.x;
    const int w = tid >> 6, l = tid & 63;
    const int c = l & 15, q = l >> 4;
    const int wq = w >> 1, wk = w & 1;          // q-half, key-half

    const u16* qg = Qb + ((size_t)bh * SEQ + qt * 32 + wq * 16) * HDIM;
    const u16* kg = Kb + ((size_t)bh * SEQ) * HDIM;
    const u16* vg = VT + ((size_t)bh * HDIM) * SEQ;

    // async staging geometry: wave w fills rows [w*16, w*16+16) of each tile.
    const int r8 = l >> 3, ch = l & 7;
    const int gch = ch ^ r8;                    // swizzle is an involution

    // Q^T B-fragments for this wave's 16 q-rows (8 VGPR)
    bf16x8 bq0 = *(const bf16x8*)&qg[c * HDIM + q * 8];
    bf16x8 bq1 = *(const bf16x8*)&qg[c * HDIM + 32 + q * 8];

    f32x4 o[4] = {};          // [db] partial O^T over this wave's 32-key slice
    float lrow = 0.f;

    const int NT = SEQ / 64;  // 32 key-tiles

#define STAGE(JT, BS) {                                                       \
    int row0 = w * 16 + r8;                                                   \
    async16(&kg[(size_t)((JT) * 64 + row0) * HDIM + gch * 8],                 \
            &Ks[BS][(w * 16) * 64 + l * 8]);                                  \
    async16(&kg[(size_t)((JT) * 64 + row0 + 8) * HDIM + gch * 8],             \
            &Ks[BS][(w * 16 + 8) * 64 + l * 8]);                              \
    async16(&vg[(size_t)row0 * SEQ + (JT) * 64 + gch * 8],                    \
            &Vs[BS][(w * 16) * 64 + l * 8]);                                  \
    async16(&vg[(size_t)(row0 + 8) * SEQ + (JT) * 64 + gch * 8],              \
            &Vs[BS][(w * 16 + 8) * 64 + l * 8]);                              \
}

#define BODY(J, BC) {                                                         \
    asm volatile("s_waitcnt vmcnt(0)" ::: "memory");                          \
    __builtin_amdgcn_s_barrier();                                             \
    if ((J) + 1 < NT) STAGE((J) + 1, (BC) ^ 1);                               \
    /* QK^T(J): A = this wave's 32 K rows (2 kb2), B = Q^T (16 q-rows) */     \
    f32x4 sc0, sc1;                                                           \
    {                                                                         \
        bf16x8 ak0 = *(const bf16x8*)&Ks[BC][(wk * 32 + c) * 64 +             \
                                             (((q    ) ^ (c & 7)) << 3)];     \
        bf16x8 ak1 = *(const bf16x8*)&Ks[BC][(wk * 32 + c) * 64 +             \
                                             (((q | 4) ^ (c & 7)) << 3)];     \
        bf16x8 bk0 = *(const bf16x8*)&Ks[BC][(wk * 32 + 16 + c) * 64 +        \
                                             (((q    ) ^ (c & 7)) << 3)];     \
        bf16x8 bk1 = *(const bf16x8*)&Ks[BC][(wk * 32 + 16 + c) * 64 +        \
                                             (((q | 4) ^ (c & 7)) << 3)];     \
        __builtin_amdgcn_s_setprio(1);                                        \
        f32x4 z0 = {}, z1 = {};                                               \
        z0 = mfma32(ak0, bq0, z0);                                            \
        sc0 = mfma32(ak1, bq1, z0);                                           \
        z1 = mfma32(bk0, bq0, z1);                                            \
        sc1 = mfma32(bk1, bq1, z1);                                           \
        __builtin_amdgcn_s_setprio(0);                                        \
    }                                                                         \
    /* exp2 softmax (log2e folded into Q) + P->bf16 B-frags */                \
    bf16x4 bp0, bp1;                                                          \
    {                                                                         \
        float p0 = exp2_hw(sc0[0]), p1 = exp2_hw(sc0[1]);                     \
        float p2 = exp2_hw(sc0[2]), p3 = exp2_hw(sc0[3]);                     \
        float p4 = exp2_hw(sc1[0]), p5 = exp2_hw(sc1[1]);                     \
        float p6 = exp2_hw(sc1[2]), p7 = exp2_hw(sc1[3]);                     \
        lrow += ((p0 + p1) + (p2 + p3)) + ((p4 + p5) + (p6 + p7));            \
        uint2 pr0, pr1;                                                       \
        pr0.x = pk2(p0, p1); pr0.y = pk2(p2, p3);                             \
        pr1.x = pk2(p4, p5); pr1.y = pk2(p6, p7);                             \
        bp0 = __builtin_bit_cast(bf16x4, pr0);                                \
        bp1 = __builtin_bit_cast(bf16x4, pr1);                                \
    }                                                                         \
    /* O^T += V^T.P^T (A = V^T frags, b64 LDS reads, 2 per db) */             \
    __builtin_amdgcn_s_setprio(1);                                            \
    _Pragma("unroll")                                                         \
    for (int db = 0; db < 4; ++db) {                                          \
        bf16x4 av0 = *(const bf16x4*)&Vs[BC][(db * 16 + c) * 64 +             \
                  (((4 * wk     + (q >> 1)) ^ (c & 7)) << 3) + ((q & 1) << 2)]; \
        bf16x4 av1 = *(const bf16x4*)&Vs[BC][(db * 16 + c) * 64 +             \
                  (((4 * wk + 2 + (q >> 1)) ^ (c & 7)) << 3) + ((q & 1) << 2)]; \
        f32x4 t = o[db];                                                      \
        t = mfma16(av0, bp0, t);                                              \
        t = mfma16(av1, bp1, t);                                              \
        o[db] = t;                                                            \
    }                                                                         \
    __builtin_amdgcn_s_setprio(0);                                            \
}

    // prologue: stage tile 0 into buffer 0
    STAGE(0, 0);

    // main: x2 unroll so buffer indices are compile-time
    for (int j2 = 0; j2 < NT; j2 += 2) {
        BODY(j2 + 0, 0);
        BODY(j2 + 1, 1);
    }
#undef STAGE
#undef BODY

    // ---- cross-wave reduction: wk-pairs combine 32-key partials ----
    lrow += __shfl_xor(lrow, 16);
    lrow += __shfl_xor(lrow, 32);

    __syncthreads();                     // all tile LDS reads done; reuse smem
    float* SCR = (float*)&Ks[0][0];      // 8KB O exchange (fits 16KB Ks)
    float* LR  = SCR + 2048;             // 32 f32 row sums

    if (wk == 1) {                       // push partials
        #pragma unroll
        for (int db = 0; db < 4; ++db)
            *(f32x4*)&SCR[((wq * 4 + db) << 8) + l * 4] = o[db];
        if (q == 0) LR[wq * 16 + c] = lrow;
    }
    __syncthreads();

    if (wk == 0) {                       // add partner, normalize, write AO
        float inv = 1.0f / (lrow + LR[wq * 16 + c]);
        const int b = bh / NHEADS, h = bh % NHEADS;
        const int s = qt * 32 + wq * 16 + c;
        u16* ao = AO + ((size_t)(b * SEQ + s)) * EMBED + h * HDIM;
        #pragma unroll
        for (int db = 0; db < 4; ++db) {
            f32x4 part = *(const f32x4*)&SCR[((wq * 4 + db) << 8) + l * 4];
            f32x4 t = o[db] + part;
            uint2 oo;
            oo.x = pk2(t[0] * inv, t[1] * inv);
            oo.y = pk2(t[2] * inv, t[3] * inv);
            *(uint2*)&ao[db * 16 + q * 4] = oo;
        }
    }
}

// ---------------------------------------------------------------------------
// Output projection (R10, frozen): 64x64 tile, BK=32, counted-vmcnt depth-2
// pipeline, NBUF=3 = 24KB. Grid (64,12)=768 blocks, 3/CU.
// ---------------------------------------------------------------------------
__global__ __launch_bounds__(256, 3)
void out_gemm(const u16* __restrict__ A, const u16* __restrict__ W,
              const float* __restrict__ bias, float* __restrict__ out)
{
    __shared__ __align__(16) u16 smem[12288];   // 24KB: 3x(As 4KB|Bs 4KB)
    const int m0 = blockIdx.x * 64;
    const int n0 = blockIdx.y * 64;
    const int tid = threadIdx.x;
    const int w = tid >> 6, l = tid & 63;
    const int c = l & 15, q = l >> 4;
    const int sr = l >> 2;
    const int gch2 = (l & 3) ^ ((l >> 3) & 3);  // (row>>1)&3 involution swizzle
    const int NK = EMBED / 32;   // 24

#define OSTAGE(KT, BS) {                                                      \
    int k0 = (KT) * 32;                                                       \
    int row = w * 16 + sr;                                                    \
    int seg = (BS) * 4096 + (w * 16) * 32;                                    \
    async16(&A[(size_t)(m0 + row) * EMBED + k0 + gch2 * 8],                   \
            &smem[seg + l * 8]);                                              \
    async16(&W[(size_t)(n0 + row) * EMBED + k0 + gch2 * 8],                   \
            &smem[seg + 2048 + l * 8]);                                       \
}

    f32x4 acc[4] = {};

#define OBODY(KT, BC, BS) {                                                   \
    if ((KT) + 1 < NK) asm volatile("s_waitcnt vmcnt(2)" ::: "memory");       \
    else               asm volatile("s_waitcnt vmcnt(0)" ::: "memory");       \
    __builtin_amdgcn_s_barrier();                                             \
    if ((KT) + 2 < NK) OSTAGE((KT) + 2, BS);                                  \
    const u16* Ab = &smem[(BC) * 4096];                                       \
    const u16* Bb = &smem[(BC) * 4096 + 2048];                                \
    const int cs = (q ^ ((c >> 1) & 3)) << 3;                                 \
    bf16x8 af = *(const bf16x8*)&Ab[(w * 16 + c) * 32 + cs];                  \
    bf16x8 bfr[4];                                                            \
    _Pragma("unroll")                                                         \
    for (int j = 0; j < 4; ++j)                                               \
        bfr[j] = *(const bf16x8*)&Bb[(j * 16 + c) * 32 + cs];                 \
    __builtin_amdgcn_s_setprio(1);                                            \
    _Pragma("unroll")                                                         \
    for (int j = 0; j < 4; ++j)                                               \
        acc[j] = mfma32(af, bfr[j], acc[j]);                                  \
    __builtin_amdgcn_s_setprio(0);                                            \
}

    OSTAGE(0, 0);
    OSTAGE(1, 1);

    for (int kt0 = 0; kt0 < NK; kt0 += 3) {
        OBODY(kt0 + 0, 0, 2);
        OBODY(kt0 + 1, 1, 0);
        OBODY(kt0 + 2, 2, 1);
    }
#undef OSTAGE
#undef OBODY

    #pragma unroll
    for (int j = 0; j < 4; ++j) {
        int n = n0 + j * 16 + c;
        float bval = bias[n];
        #pragma unroll
        for (int r = 0; r < 4; ++r) {
            int m = m0 + w * 16 + q * 4 + r;
            out[(size_t)m * EMBED + n] = acc[j][r] + bval;
        }
    }
}

// ---------------------------------------------------------------------------
extern "C" void kernel_launch(void* const* d_in, const int* in_sizes, int n_in,
                              void* d_out, int out_size, void* d_ws, size_t ws_size,
                              hipStream_t stream)
{
    const float* x    = (const float*)d_in[0];
    const float* wqkv = (const float*)d_in[1];
    const float* bqkv = (const float*)d_in[2];
    const float* wout = (const float*)d_in[3];
    const float* bout = (const float*)d_in[4];
    float* out = (float*)d_out;

    const int nx  = NTOK * EMBED;         // 3,145,728
    const int nwq = QKV_N * EMBED;        // 1,769,472
    const int nwo = EMBED * EMBED;        //   589,824
    const size_t per = (size_t)NBATCH * NHEADS * SEQ * HDIM;  // 3,145,728

    u16* xb    = (u16*)d_ws;
    u16* wqkvb = xb + nx;
    u16* woutb = wqkvb + nwq;
    u16* Qb    = woutb + nwo;
    u16* Kb    = Qb + per;
    u16* VT    = Kb + per;
    u16* AO    = VT + per;   // [token][EMBED] bf16, written directly by attn

    int castTot = (nx + nwq + nwo) / 4;
    cast_kernel<<<castTot / 256, 256, 0, stream>>>(x, xb, nx, wqkv, wqkvb, nwq, wout, woutb, nwo);

    dim3 g1(NTOK / 128, QKV_N / 128);     // (32, 18)
    qkv_gemm<<<g1, 256, 0, stream>>>(xb, wqkvb, bqkv, Qb, Kb, VT);

    attn_kernel<<<BHTOT * 64, 256, 0, stream>>>(Qb, Kb, VT, AO);   // 1536 blocks, 5/CU

    dim3 g3(NTOK / 64, EMBED / 64);       // (64, 12) = 768 blocks, 3/CU balanced
    out_gemm<<<g3, 256, 0, stream>>>(AO, woutb, bout, out);
}

// Round 12
// 159.141 us; speedup vs baseline: 1.0435x; 1.0435x over previous
//
#include <hip/hip_runtime.h>
#include <hip/hip_bf16.h>
#include <math.h>

typedef unsigned short u16;
typedef unsigned int u32;
typedef __attribute__((ext_vector_type(8))) short bf16x8;   // 8 bf16 = 4 VGPRs
typedef __attribute__((ext_vector_type(4))) short bf16x4;   // 4 bf16 = 2 VGPRs
typedef __attribute__((ext_vector_type(4))) float f32x4;

#define EMBED 768
#define NHEADS 12
#define HDIM 64
#define NBATCH 2
#define SEQ 2048
#define NTOK 4096
#define QKV_N 2304
#define BHTOT 24        // NBATCH*NHEADS
// Q scale folds softmax's 1/sqrt(d) AND log2(e) so attn can use raw v_exp_f32
#define QSCALE 0.18033688011112042f   // 0.125 * log2(e)

__device__ __forceinline__ u16 f2b(float f) {
    __hip_bfloat16 h = __float2bfloat16(f);
    return __builtin_bit_cast(u16, h);
}
__device__ __forceinline__ u32 pk2(float a, float b) {
    return (u32)f2b(a) | ((u32)f2b(b) << 16);
}
__device__ __forceinline__ f32x4 mfma32(bf16x8 a, bf16x8 b, f32x4 c) {
    return __builtin_amdgcn_mfma_f32_16x16x32_bf16(a, b, c, 0, 0, 0);
}
// K=16 MFMA: B-operand layout == C/D layout -> P feeds PV from registers.
#if __has_builtin(__builtin_amdgcn_mfma_f32_16x16x16_bf16)
__device__ __forceinline__ f32x4 mfma16(bf16x4 a, bf16x4 b, f32x4 c) {
    return __builtin_amdgcn_mfma_f32_16x16x16_bf16(a, b, c, 0, 0, 0);
}
#else
__device__ __forceinline__ f32x4 mfma16(bf16x4 a, bf16x4 b, f32x4 c) {
    return __builtin_amdgcn_mfma_f32_16x16x16bf16_1k(a, b, c, 0, 0, 0);
}
#endif

// guaranteed single-instruction 2^x (never libm)
__device__ __forceinline__ float exp2_hw(float x) {
#if __has_builtin(__builtin_amdgcn_exp2f)
    return __builtin_amdgcn_exp2f(x);
#else
    float r;
    asm("v_exp_f32 %0, %1" : "=v"(r) : "v"(x));
    return r;
#endif
}

// async global->LDS, 16B per lane. LDS dest must be base + lane*16 in lane
// order (HW constraint); our swizzle lives on the GLOBAL address side.
__device__ __forceinline__ void async16(const u16* g, u16* l) {
    __builtin_amdgcn_global_load_lds(
        (const __attribute__((address_space(1))) unsigned int*)g,
        (__attribute__((address_space(3))) unsigned int*)l,
        16, 0, 0);
}

// ---------------------------------------------------------------------------
// QKV projection R12: cast FUSED. Reads x and w_qkv as f32, converts during
// reg-staged LDS writes (cast_kernel deleted -> one fewer launch + no bf16
// intermediate round-trip for x/wqkv). T14-style split gives the loads a
// full body (~800cy) of cover: loads for tile J+2 issued at body J, written
// (cvt + swizzled ds_write_b128) at body J+1, computed at body J+2 -> the
// __syncthreads drain at each body only hits loads issued a whole body ago
// (unlike R0's 50cy-cover failure). Swizzle moves to the ds_write side
// (identical involution: chunk ^ (row>>1)&3), compute-side reads unchanged.
// 128x128 tile, BK=32, NK=24, 2 LDS buffers (32KB) + T-scratch (36KB union).
// ---------------------------------------------------------------------------
__global__ __launch_bounds__(256, 3)
void qkv_gemm(const float* __restrict__ A, const float* __restrict__ W,
              const float* __restrict__ bias,
              u16* __restrict__ Qb, u16* __restrict__ Kb, u16* __restrict__ VT)
{
    __shared__ __align__(16) u16 smem[18432];   // 36KB: staging 2x(A 8KB|B 8KB)=32KB; T 36KB
    const int m0 = blockIdx.x * 128;
    const int n0 = blockIdx.y * 128;
    const int tid = threadIdx.x;
    const int w = tid >> 6, l = tid & 63;
    const int c = l & 15, q = l >> 4;
    const int wm = (w >> 1) * 64, wn = (w & 1) * 64;
    const int sr = l >> 2;                      // 16 rows/wave/j-iter
    const int chs = ((l & 3) ^ ((l >> 3) & 3)) * 8;   // swizzled chunk (u16 units)
    const int NK = EMBED / 32;   // 24

    float4 ra[2][2], rb[2][2];   // staged f32: [j][half], 32 VGPR

#define QLOAD(KT) {                                                           \
    int k0 = (KT) * 32;                                                       \
    _Pragma("unroll")                                                         \
    for (int j = 0; j < 2; ++j) {                                             \
        int row = j * 64 + w * 16 + sr;                                       \
        const float* pa = &A[(size_t)(m0 + row) * EMBED + k0 + (l & 3) * 8];  \
        const float* pb = &W[(size_t)(n0 + row) * EMBED + k0 + (l & 3) * 8];  \
        ra[j][0] = *(const float4*)pa; ra[j][1] = *(const float4*)(pa + 4);   \
        rb[j][0] = *(const float4*)pb; rb[j][1] = *(const float4*)(pb + 4);   \
    }                                                                         \
}

#define QWRITE(BS) {                                                          \
    _Pragma("unroll")                                                         \
    for (int j = 0; j < 2; ++j) {                                             \
        int row = j * 64 + w * 16 + sr;                                       \
        uint4 pa, pb;                                                         \
        pa.x = pk2(ra[j][0].x, ra[j][0].y); pa.y = pk2(ra[j][0].z, ra[j][0].w); \
        pa.z = pk2(ra[j][1].x, ra[j][1].y); pa.w = pk2(ra[j][1].z, ra[j][1].w); \
        pb.x = pk2(rb[j][0].x, rb[j][0].y); pb.y = pk2(rb[j][0].z, rb[j][0].w); \
        pb.z = pk2(rb[j][1].x, rb[j][1].y); pb.w = pk2(rb[j][1].z, rb[j][1].w); \
        *(uint4*)&smem[(BS) * 8192 + row * 32 + chs] = pa;                    \
        *(uint4*)&smem[(BS) * 8192 + 4096 + row * 32 + chs] = pb;             \
    }                                                                         \
}

    f32x4 acc[4][4] = {};

#define QBODY(KT, BC) {                                                       \
    __syncthreads();          /* buf BC visible; drains loads (1-body-old) */ \
    if ((KT) + 1 < NK) QWRITE((BC) ^ 1);                                      \
    if ((KT) + 2 < NK) QLOAD((KT) + 2);                                       \
    const u16* Ab = &smem[(BC) * 8192];                                       \
    const u16* Bb = &smem[(BC) * 8192 + 4096];                                \
    const int cs = (q ^ ((c >> 1) & 3)) << 3;                                 \
    bf16x8 af[4], bfr[4];                                                     \
    _Pragma("unroll")                                                         \
    for (int i = 0; i < 4; ++i)                                               \
        af[i] = *(const bf16x8*)&Ab[(wm + i * 16 + c) * 32 + cs];             \
    _Pragma("unroll")                                                         \
    for (int j = 0; j < 4; ++j)                                               \
        bfr[j] = *(const bf16x8*)&Bb[(wn + j * 16 + c) * 32 + cs];            \
    __builtin_amdgcn_s_setprio(1);                                            \
    _Pragma("unroll")                                                         \
    for (int i = 0; i < 4; ++i)                                               \
        _Pragma("unroll")                                                     \
        for (int j = 0; j < 4; ++j)                                           \
            acc[i][j] = mfma32(af[i], bfr[j], acc[i][j]);                     \
    __builtin_amdgcn_s_setprio(0);                                            \
}

    // prologue: tile 0 -> regs -> buf0 (compiler waits the loads); issue tile 1
    QLOAD(0);
    QWRITE(0);
    QLOAD(1);

    for (int kt0 = 0; kt0 < NK; kt0 += 2) {
        QBODY(kt0 + 0, 0);
        QBODY(kt0 + 1, 1);
    }
#undef QLOAD
#undef QWRITE
#undef QBODY

    const int p = n0 / EMBED;                 // 0=q,1=k,2=v (block-uniform)
    const int ncol0 = n0 + wn;
    const int h = (ncol0 % EMBED) / HDIM;
    const int mrow0 = m0 + wm;
    const int b = mrow0 >> 11;
    const int s0 = mrow0 & (SEQ - 1);

    if (p < 2) {
        u16* dst = (p == 0) ? Qb : Kb;
        const float mul = (p == 0) ? QSCALE : 1.0f;
        #pragma unroll
        for (int j = 0; j < 4; ++j) {
            int n = ncol0 + j * 16 + c;
            int d = j * 16 + c;
            float bval = bias[n];
            #pragma unroll
            for (int i = 0; i < 4; ++i) {
                #pragma unroll
                for (int r = 0; r < 4; ++r) {
                    int s = s0 + i * 16 + q * 4 + r;
                    float v = (acc[i][j][r] + bval) * mul;
                    dst[(((size_t)(b * NHEADS + h)) * SEQ + s) * HDIM + d] = f2b(v);
                }
            }
        }
    } else {
        __syncthreads();                      // all MFMA LDS reads done
        u16* T = smem + w * (64 * 72);        // wave-private scratch (36KB)
        #pragma unroll
        for (int j = 0; j < 4; ++j) {
            int n = ncol0 + j * 16 + c;
            float bval = bias[n];
            #pragma unroll
            for (int i = 0; i < 4; ++i) {
                uint2 pr;
                pr.x = pk2(acc[i][j][0] + bval, acc[i][j][1] + bval);
                pr.y = pk2(acc[i][j][2] + bval, acc[i][j][3] + bval);
                *(uint2*)&T[(j * 16 + c) * 72 + i * 16 + q * 4] = pr;
            }
        }
        const size_t vtbase = ((size_t)(b * NHEADS + h)) * HDIM * SEQ + s0;
        #pragma unroll
        for (int ii = 0; ii < 8; ++ii) {
            int d = (l >> 3) + 8 * ii;
            int sch = (l & 7) * 8;
            uint4 vv = *(const uint4*)&T[d * 72 + sch];
            *(uint4*)&VT[vtbase + (size_t)d * SEQ + sch] = vv;
        }
    }
}

// ---------------------------------------------------------------------------
// Flash attention (R10, frozen — proven 47.3us): 2x2 KEY/Q split, K+V in LDS
// staged depth-2, software pipeline (QK^T j+1 overlaps softmax+PV j), NBUF=3,
// x6 unroll, 768 blocks (3/CU).
// ---------------------------------------------------------------------------
__global__ __launch_bounds__(256, 3)
void attn_kernel(const u16* __restrict__ Qb, const u16* __restrict__ Kb,
                 const u16* __restrict__ VT, u16* __restrict__ AO)
{
    __shared__ __align__(16) u16 Ks[3][4096];   // [buf][64 keys x 64 d] swizzled
    __shared__ __align__(16) u16 Vs[3][4096];   // [buf][64 d x 64 keys] swizzled

    const int blk = blockIdx.x;
    const int g = blk & 7, kk = blk >> 3;       // g -> XCD (round-robin heuristic)
    const int bh = g * 3 + (kk >> 5);           // same-bh blocks share an XCD (KV L2 reuse)
    const int qt = kk & 31;

    const int tid = threadIdx.x;
    const int w = tid >> 6, l = tid & 63;
    const int c = l & 15, q = l >> 4;
    const int wq = w >> 1, wk = w & 1;          // q-half, key-half

    const u16* qg = Qb + ((size_t)bh * SEQ + qt * 64 + wq * 32) * HDIM;
    const u16* kg = Kb + ((size_t)bh * SEQ) * HDIM;
    const u16* vg = VT + ((size_t)bh * HDIM) * SEQ;

    // async staging geometry: wave w fills rows [w*16, w*16+16) of each tile.
    const int r8 = l >> 3, ch = l & 7;
    const int gch = ch ^ r8;                    // swizzle is an involution

    // Q^T B-fragments for this wave's 2 q-blocks (16 VGPR)
    bf16x8 bq[2][2];
    #pragma unroll
    for (int qb2 = 0; qb2 < 2; ++qb2) {
        bq[qb2][0] = *(const bf16x8*)&qg[(qb2 * 16 + c) * HDIM + q * 8];
        bq[qb2][1] = *(const bf16x8*)&qg[(qb2 * 16 + c) * HDIM + 32 + q * 8];
    }

    f32x4 o[4][2] = {};                 // [db][qb2] partial O^T over 32-key slice
    float lrow[2] = {0.f, 0.f};         // per-qb2 partial row sums

    const int NT = SEQ / 64;   // 32

#define STAGE(JT, BS) {                                                       \
    int row0 = w * 16 + r8;                                                   \
    async16(&kg[(size_t)((JT) * 64 + row0) * HDIM + gch * 8],                 \
            &Ks[BS][(w * 16) * 64 + l * 8]);                                  \
    async16(&vg[(size_t)row0 * SEQ + (JT) * 64 + gch * 8],                    \
            &Vs[BS][(w * 16) * 64 + l * 8]);                                  \
    async16(&kg[(size_t)((JT) * 64 + row0 + 8) * HDIM + gch * 8],             \
            &Ks[BS][(w * 16 + 8) * 64 + l * 8]);                              \
    async16(&vg[(size_t)(row0 + 8) * SEQ + (JT) * 64 + gch * 8],              \
            &Vs[BS][(w * 16 + 8) * 64 + l * 8]);                              \
}

    // S_slice^T[key][qrow]: A = 32 K rows (2 kb2), B = Q^T (2 qb2 blocks)
#define QKT(SN, BN) {                                                         \
    __builtin_amdgcn_s_setprio(1);                                            \
    _Pragma("unroll")                                                         \
    for (int kb2 = 0; kb2 < 2; ++kb2) {                                       \
        bf16x8 ak0 = *(const bf16x8*)&Ks[BN][(wk * 32 + kb2 * 16 + c) * 64 +  \
                                             (((q    ) ^ (c & 7)) << 3)];     \
        bf16x8 ak1 = *(const bf16x8*)&Ks[BN][(wk * 32 + kb2 * 16 + c) * 64 +  \
                                             (((q | 4) ^ (c & 7)) << 3)];     \
        _Pragma("unroll")                                                     \
        for (int qb2 = 0; qb2 < 2; ++qb2) {                                   \
            f32x4 zz = {};                                                    \
            zz = mfma32(ak0, bq[qb2][0], zz);                                 \
            SN[kb2][qb2] = mfma32(ak1, bq[qb2][1], zz);                       \
        }                                                                     \
    }                                                                         \
    __builtin_amdgcn_s_setprio(0);                                            \
}

    // exp2 softmax (log2e folded into Q), P->bf16 frags, O^T += V^T.P^T
#define SOFTPV(SC, BC) {                                                      \
    _Pragma("unroll")                                                         \
    for (int kb2 = 0; kb2 < 2; ++kb2)                                         \
        _Pragma("unroll")                                                     \
        for (int qb2 = 0; qb2 < 2; ++qb2) {                                   \
            float p0 = exp2_hw(SC[kb2][qb2][0]);                              \
            float p1 = exp2_hw(SC[kb2][qb2][1]);                              \
            float p2 = exp2_hw(SC[kb2][qb2][2]);                              \
            float p3 = exp2_hw(SC[kb2][qb2][3]);                              \
            SC[kb2][qb2][0] = p0; SC[kb2][qb2][1] = p1;                       \
            SC[kb2][qb2][2] = p2; SC[kb2][qb2][3] = p3;                       \
            lrow[qb2] += (p0 + p1) + (p2 + p3);                               \
        }                                                                     \
    bf16x4 bp[2][2];                                                          \
    _Pragma("unroll")                                                         \
    for (int kb2 = 0; kb2 < 2; ++kb2)                                         \
        _Pragma("unroll")                                                     \
        for (int qb2 = 0; qb2 < 2; ++qb2) {                                   \
            uint2 pr;                                                         \
            pr.x = pk2(SC[kb2][qb2][0], SC[kb2][qb2][1]);                     \
            pr.y = pk2(SC[kb2][qb2][2], SC[kb2][qb2][3]);                     \
            bp[kb2][qb2] = __builtin_bit_cast(bf16x4, pr);                    \
        }                                                                     \
    __builtin_amdgcn_s_setprio(1);                                            \
    _Pragma("unroll")                                                         \
    for (int db = 0; db < 4; ++db) {                                          \
        bf16x4 av0 = *(const bf16x4*)&Vs[BC][(db * 16 + c) * 64 +             \
                  (((4 * wk     + (q >> 1)) ^ (c & 7)) << 3) + ((q & 1) << 2)]; \
        bf16x4 av1 = *(const bf16x4*)&Vs[BC][(db * 16 + c) * 64 +             \
                  (((4 * wk + 2 + (q >> 1)) ^ (c & 7)) << 3) + ((q & 1) << 2)]; \
        _Pragma("unroll")                                                     \
        for (int qb2 = 0; qb2 < 2; ++qb2) {                                   \
            o[db][qb2] = mfma16(av0, bp[0][qb2], o[db][qb2]);                 \
            o[db][qb2] = mfma16(av1, bp[1][qb2], o[db][qb2]);                 \
        }                                                                     \
    }                                                                         \
    __builtin_amdgcn_s_setprio(0);                                            \
}

#define BODY(J, SC, SN, BC, BN, BS) {                                         \
    asm volatile("s_waitcnt vmcnt(0)" ::: "memory");                          \
    __builtin_amdgcn_s_barrier();                                             \
    if ((J) + 2 < NT) STAGE((J) + 2, BS);                                     \
    if ((J) + 1 < NT) QKT(SN, BN);                                            \
    SOFTPV(SC, BC);                                                           \
}

    f32x4 scA[2][2], scB[2][2];

    // prologue: stage tiles 0,1; compute QK^T(0)
    STAGE(0, 0);
    STAGE(1, 1);
    asm volatile("s_waitcnt vmcnt(4)" ::: "memory");   // tile 0 landed
    __builtin_amdgcn_s_barrier();
    QKT(scA, 0);

    // main: 30 bodies; all buffer/S indices compile-time (x6 unroll)
    for (int jb = 0; jb < 30; jb += 6) {
        BODY(jb + 0, scA, scB, 0, 1, 2);
        BODY(jb + 1, scB, scA, 1, 2, 0);
        BODY(jb + 2, scA, scB, 2, 0, 1);
        BODY(jb + 3, scB, scA, 0, 1, 2);
        BODY(jb + 4, scA, scB, 1, 2, 0);
        BODY(jb + 5, scB, scA, 2, 0, 1);
    }
    // tail: j=30 (stage guard off, computes QK^T(31)), then j=31 (no next)
    BODY(30, scA, scB, 0, 1, 2);
    SOFTPV(scB, 1);                      // j=31: V[31] in buf 31%3==1, landed

#undef STAGE
#undef QKT
#undef SOFTPV
#undef BODY

    // ---- cross-wave reduction: wk-pairs combine 32-key partials ----
    #pragma unroll
    for (int qb2 = 0; qb2 < 2; ++qb2) {
        lrow[qb2] += __shfl_xor(lrow[qb2], 16);
        lrow[qb2] += __shfl_xor(lrow[qb2], 32);
    }

    __syncthreads();                     // all tile LDS reads done; reuse smem
    float* SCR = (float*)&Ks[0][0];      // 16KB O exchange + 256B row sums
    float* LR  = SCR + 4096;

    if (wk == 1) {                       // push partials
        #pragma unroll
        for (int db = 0; db < 4; ++db)
            #pragma unroll
            for (int qb2 = 0; qb2 < 2; ++qb2)
                *(f32x4*)&SCR[((wq * 8 + db * 2 + qb2) << 8) + l * 4] = o[db][qb2];
        if (q == 0) {
            LR[(wq * 2 + 0) * 16 + c] = lrow[0];
            LR[(wq * 2 + 1) * 16 + c] = lrow[1];
        }
    }
    __syncthreads();

    if (wk == 0) {                       // add partner, normalize, write
        float inv[2];
        #pragma unroll
        for (int qb2 = 0; qb2 < 2; ++qb2)
            inv[qb2] = 1.0f / (lrow[qb2] + LR[(wq * 2 + qb2) * 16 + c]);
        const int b = bh / NHEADS, h = bh % NHEADS;
        #pragma unroll
        for (int qb2 = 0; qb2 < 2; ++qb2) {
            const int s = qt * 64 + wq * 32 + qb2 * 16 + c;
            u16* ao = AO + ((size_t)(b * SEQ + s)) * EMBED + h * HDIM;
            #pragma unroll
            for (int db = 0; db < 4; ++db) {
                f32x4 part = *(const f32x4*)&SCR[((wq * 8 + db * 2 + qb2) << 8) + l * 4];
                f32x4 t = o[db][qb2] + part;
                uint2 oo;
                oo.x = pk2(t[0] * inv[qb2], t[1] * inv[qb2]);
                oo.y = pk2(t[2] * inv[qb2], t[3] * inv[qb2]);
                *(uint2*)&ao[db * 16 + q * 4] = oo;
            }
        }
    }
}

// ---------------------------------------------------------------------------
// Output projection R12: cast FUSED for w_out (f32 -> reg-stage cvt -> LDS).
// A (AO, bf16) keeps async16 staging, issued one body ahead so the
// __syncthreads drain is harmless. 64x64 tile, BK=32, 2 buffers (16KB).
// Grid (64,12)=768 blocks, 3/CU.
// ---------------------------------------------------------------------------
__global__ __launch_bounds__(256)
void out_gemm(const u16* __restrict__ A, const float* __restrict__ W,
              const float* __restrict__ bias, float* __restrict__ out)
{
    __shared__ __align__(16) u16 smem[8192];    // 16KB: 2x(A 4KB|B 4KB)
    const int m0 = blockIdx.x * 64;
    const int n0 = blockIdx.y * 64;
    const int tid = threadIdx.x;
    const int w = tid >> 6, l = tid & 63;
    const int c = l & 15, q = l >> 4;
    const int sr = l >> 2;
    const int gch2 = (l & 3) ^ ((l >> 3) & 3);  // involution swizzle (chunk units)
    const int chs = gch2 * 8;                   // u16 offset for ds_write side
    const int NK = EMBED / 32;   // 24

    float4 rb[2];   // staged f32 B: 8 VGPR

#define OBLOAD(KT) {                                                          \
    int k0 = (KT) * 32;                                                       \
    int row = w * 16 + sr;                                                    \
    const float* pb = &W[(size_t)(n0 + row) * EMBED + k0 + (l & 3) * 8];      \
    rb[0] = *(const float4*)pb; rb[1] = *(const float4*)(pb + 4);             \
}

#define OBWRITE(BS) {                                                         \
    int row = w * 16 + sr;                                                    \
    uint4 pb;                                                                 \
    pb.x = pk2(rb[0].x, rb[0].y); pb.y = pk2(rb[0].z, rb[0].w);               \
    pb.z = pk2(rb[1].x, rb[1].y); pb.w = pk2(rb[1].z, rb[1].w);               \
    *(uint4*)&smem[(BS) * 4096 + 2048 + row * 32 + chs] = pb;                 \
}

#define OAASYNC(KT, BS) {                                                     \
    int k0 = (KT) * 32;                                                       \
    int row = w * 16 + sr;                                                    \
    async16(&A[(size_t)(m0 + row) * EMBED + k0 + gch2 * 8],                   \
            &smem[(BS) * 4096 + (w * 16) * 32 + l * 8]);                      \
}

    f32x4 acc[4] = {};

#define OBODY(KT, BC) {                                                       \
    __syncthreads();   /* buf BC visible; drains 1-body-old async16/loads */  \
    if ((KT) + 1 < NK) { OBWRITE((BC) ^ 1); OAASYNC((KT) + 1, (BC) ^ 1); }    \
    if ((KT) + 2 < NK) OBLOAD((KT) + 2);                                      \
    const u16* Ab = &smem[(BC) * 4096];                                       \
    const u16* Bb = &smem[(BC) * 4096 + 2048];                                \
    const int cs = (q ^ ((c >> 1) & 3)) << 3;                                 \
    bf16x8 af = *(const bf16x8*)&Ab[(w * 16 + c) * 32 + cs];                  \
    bf16x8 bfr[4];                                                            \
    _Pragma("unroll")                                                         \
    for (int j = 0; j < 4; ++j)                                               \
        bfr[j] = *(const bf16x8*)&Bb[(j * 16 + c) * 32 + cs];                 \
    __builtin_amdgcn_s_setprio(1);                                            \
    _Pragma("unroll")                                                         \
    for (int j = 0; j < 4; ++j)                                               \
        acc[j] = mfma32(af, bfr[j], acc[j]);                                  \
    __builtin_amdgcn_s_setprio(0);                                            \
}

    // prologue: B tile0 -> regs -> buf0; A tile0 async; issue B tile1 loads
    OBLOAD(0);
    OBWRITE(0);
    OAASYNC(0, 0);
    OBLOAD(1);

    for (int kt0 = 0; kt0 < NK; kt0 += 2) {
        OBODY(kt0 + 0, 0);
        OBODY(kt0 + 1, 1);
    }
#undef OBLOAD
#undef OBWRITE
#undef OAASYNC
#undef OBODY

    #pragma unroll
    for (int j = 0; j < 4; ++j) {
        int n = n0 + j * 16 + c;
        float bval = bias[n];
        #pragma unroll
        for (int r = 0; r < 4; ++r) {
            int m = m0 + w * 16 + q * 4 + r;
            out[(size_t)m * EMBED + n] = acc[j][r] + bval;
        }
    }
}

// ---------------------------------------------------------------------------
extern "C" void kernel_launch(void* const* d_in, const int* in_sizes, int n_in,
                              void* d_out, int out_size, void* d_ws, size_t ws_size,
                              hipStream_t stream)
{
    const float* x    = (const float*)d_in[0];
    const float* wqkv = (const float*)d_in[1];
    const float* bqkv = (const float*)d_in[2];
    const float* wout = (const float*)d_in[3];
    const float* bout = (const float*)d_in[4];
    float* out = (float*)d_out;

    const size_t per = (size_t)NBATCH * NHEADS * SEQ * HDIM;  // 3,145,728

    u16* Qb = (u16*)d_ws;
    u16* Kb = Qb + per;
    u16* VT = Kb + per;
    u16* AO = VT + per;   // [token][EMBED] bf16, written directly by attn

    dim3 g1(NTOK / 128, QKV_N / 128);     // (32, 18)
    qkv_gemm<<<g1, 256, 0, stream>>>(x, wqkv, bqkv, Qb, Kb, VT);

    attn_kernel<<<BHTOT * 32, 256, 0, stream>>>(Qb, Kb, VT, AO);   // 768 blocks

    dim3 g3(NTOK / 64, EMBED / 64);       // (64, 12) = 768 blocks, 3/CU balanced
    out_gemm<<<g3, 256, 0, stream>>>(AO, wout, bout, out);
}

// Round 13
// 150.945 us; speedup vs baseline: 1.1002x; 1.0543x over previous
//
#include <hip/hip_runtime.h>
#include <hip/hip_bf16.h>
#include <math.h>

typedef unsigned short u16;
typedef unsigned int u32;
typedef __attribute__((ext_vector_type(8))) short bf16x8;   // 8 bf16 = 4 VGPRs
typedef __attribute__((ext_vector_type(4))) short bf16x4;   // 4 bf16 = 2 VGPRs
typedef __attribute__((ext_vector_type(4))) float f32x4;

#define EMBED 768
#define NHEADS 12
#define HDIM 64
#define NBATCH 2
#define SEQ 2048
#define NTOK 4096
#define QKV_N 2304
#define BHTOT 24        // NBATCH*NHEADS
// Q scale folds softmax's 1/sqrt(d) AND log2(e) so attn can use raw v_exp_f32
#define QSCALE 0.18033688011112042f   // 0.125 * log2(e)

__device__ __forceinline__ u16 f2b(float f) {
    __hip_bfloat16 h = __float2bfloat16(f);
    return __builtin_bit_cast(u16, h);
}
__device__ __forceinline__ u32 pk2(float a, float b) {
    return (u32)f2b(a) | ((u32)f2b(b) << 16);
}
__device__ __forceinline__ f32x4 mfma32(bf16x8 a, bf16x8 b, f32x4 c) {
    return __builtin_amdgcn_mfma_f32_16x16x32_bf16(a, b, c, 0, 0, 0);
}
// K=16 MFMA: B-operand layout == C/D layout -> P feeds PV from registers.
#if __has_builtin(__builtin_amdgcn_mfma_f32_16x16x16_bf16)
__device__ __forceinline__ f32x4 mfma16(bf16x4 a, bf16x4 b, f32x4 c) {
    return __builtin_amdgcn_mfma_f32_16x16x16_bf16(a, b, c, 0, 0, 0);
}
#else
__device__ __forceinline__ f32x4 mfma16(bf16x4 a, bf16x4 b, f32x4 c) {
    return __builtin_amdgcn_mfma_f32_16x16x16bf16_1k(a, b, c, 0, 0, 0);
}
#endif

// guaranteed single-instruction 2^x (never libm)
__device__ __forceinline__ float exp2_hw(float x) {
#if __has_builtin(__builtin_amdgcn_exp2f)
    return __builtin_amdgcn_exp2f(x);
#else
    float r;
    asm("v_exp_f32 %0, %1" : "=v"(r) : "v"(x));
    return r;
#endif
}

// async global->LDS, 16B per lane. LDS dest must be base + lane*16 in lane
// order (HW constraint); our swizzle lives on the GLOBAL address side.
__device__ __forceinline__ void async16(const u16* g, u16* l) {
    __builtin_amdgcn_global_load_lds(
        (const __attribute__((address_space(1))) unsigned int*)g,
        (__attribute__((address_space(3))) unsigned int*)l,
        16, 0, 0);
}

// ---------------------------------------------------------------------------
// fp32 -> bf16 cast for x, w_qkv, w_out
// ---------------------------------------------------------------------------
__global__ __launch_bounds__(256)
void cast_kernel(const float* __restrict__ s0, u16* __restrict__ d0, int n0,
                 const float* __restrict__ s1, u16* __restrict__ d1, int n1,
                 const float* __restrict__ s2, u16* __restrict__ d2, int n2)
{
    int idx = (blockIdx.x * 256 + threadIdx.x) * 4;
    const float* s; u16* d; int i;
    if (idx < n0)            { s = s0; d = d0; i = idx; }
    else if (idx < n0 + n1)  { s = s1; d = d1; i = idx - n0; }
    else                     { s = s2; d = d2; i = idx - n0 - n1; if (i >= n2) return; }
    float4 v = *(const float4*)&s[i];
    ushort4 o;
    o.x = f2b(v.x); o.y = f2b(v.y); o.z = f2b(v.z); o.w = f2b(v.w);
    *(ushort4*)&d[i] = o;
}

// ---------------------------------------------------------------------------
// QKV projection (R7, best-measured): 128x128 tile, BK=32, NK=24. Staging
// LDS 32KB (block 36KB with T-scratch) -> 4 blocks/CU. async16-after-barrier
// pipeline. 64B rows (4x16B chunks), swizzle ch ^ ((row>>1)&3).
// Epilogue: Q(*QSCALE)/K scatter; V transposed through T -> V^T.
// ---------------------------------------------------------------------------
__global__ __launch_bounds__(256, 4)
void qkv_gemm(const u16* __restrict__ A, const u16* __restrict__ W,
              const float* __restrict__ bias,
              u16* __restrict__ Qb, u16* __restrict__ Kb, u16* __restrict__ VT)
{
    __shared__ __align__(16) u16 smem[18432];   // As[2]|Bs[2] staging 32KB; T[4][64*72] 36KB
    u16* As = smem;                             // [buf][128 rows x 32 cols] swizzled
    u16* Bs = smem + 8192;
    const int m0 = blockIdx.x * 128;
    const int n0 = blockIdx.y * 128;
    const int tid = threadIdx.x;
    const int w = tid >> 6, l = tid & 63;
    const int c = l & 15, q = l >> 4;
    const int wm = (w >> 1) * 64, wn = (w & 1) * 64;
    // staging: instr j covers rows j*64 + w*16 + (l>>2); chunk l&3 of 64B row
    const int sr = l >> 2;
    const int gch2 = (l & 3) ^ ((l >> 3) & 3);  // (row>>1)&3 involution swizzle

    // stage K-tile 0 into buffer 0
    #pragma unroll
    for (int j = 0; j < 2; ++j) {
        int row = j * 64 + w * 16 + sr;
        int seg = (j * 64 + w * 16) * 32;
        async16(&A[(size_t)(m0 + row) * EMBED + gch2 * 8], &As[seg + l * 8]);
        async16(&W[(size_t)(n0 + row) * EMBED + gch2 * 8], &Bs[seg + l * 8]);
    }

    f32x4 acc[4][4] = {};
    const int NK = EMBED / 32;   // 24

    #pragma unroll 2
    for (int kt = 0; kt < NK; ++kt) {
        const int cur = kt & 1;
        __syncthreads();          // drains tile kt's loads; prev buffer readers done
        if (kt + 1 < NK) {        // issue kt+1 (lands during compute of kt)
            int k0 = (kt + 1) * 32;
            #pragma unroll
            for (int j = 0; j < 2; ++j) {
                int row = j * 64 + w * 16 + sr;
                int seg = (cur ^ 1) * 4096 + (j * 64 + w * 16) * 32;
                async16(&A[(size_t)(m0 + row) * EMBED + k0 + gch2 * 8], &As[seg + l * 8]);
                async16(&W[(size_t)(n0 + row) * EMBED + k0 + gch2 * 8], &Bs[seg + l * 8]);
            }
        }
        const u16* Ab = As + cur * 4096;
        const u16* Bb = Bs + cur * 4096;
        const int cs = (q ^ ((c >> 1) & 3)) << 3;   // swizzled chunk (full BK=32 row)
        bf16x8 af[4], bfr[4];
        #pragma unroll
        for (int i = 0; i < 4; ++i)
            af[i] = *(const bf16x8*)&Ab[(wm + i * 16 + c) * 32 + cs];
        #pragma unroll
        for (int j = 0; j < 4; ++j)
            bfr[j] = *(const bf16x8*)&Bb[(wn + j * 16 + c) * 32 + cs];
        #pragma unroll
        for (int i = 0; i < 4; ++i)
            #pragma unroll
            for (int j = 0; j < 4; ++j)
                acc[i][j] = mfma32(af[i], bfr[j], acc[i][j]);
    }

    const int p = n0 / EMBED;                 // 0=q,1=k,2=v (block-uniform)
    const int ncol0 = n0 + wn;
    const int h = (ncol0 % EMBED) / HDIM;
    const int mrow0 = m0 + wm;
    const int b = mrow0 >> 11;
    const int s0 = mrow0 & (SEQ - 1);

    if (p < 2) {
        u16* dst = (p == 0) ? Qb : Kb;
        const float mul = (p == 0) ? QSCALE : 1.0f;
        #pragma unroll
        for (int j = 0; j < 4; ++j) {
            int n = ncol0 + j * 16 + c;
            int d = j * 16 + c;
            float bval = bias[n];
            #pragma unroll
            for (int i = 0; i < 4; ++i) {
                #pragma unroll
                for (int r = 0; r < 4; ++r) {
                    int s = s0 + i * 16 + q * 4 + r;
                    float v = (acc[i][j][r] + bval) * mul;
                    dst[(((size_t)(b * NHEADS + h)) * SEQ + s) * HDIM + d] = f2b(v);
                }
            }
        }
    } else {
        __syncthreads();                      // all MFMA LDS reads done
        u16* T = smem + w * (64 * 72);        // wave-private scratch
        #pragma unroll
        for (int j = 0; j < 4; ++j) {
            int n = ncol0 + j * 16 + c;
            float bval = bias[n];
            #pragma unroll
            for (int i = 0; i < 4; ++i) {
                uint2 pr;
                pr.x = pk2(acc[i][j][0] + bval, acc[i][j][1] + bval);
                pr.y = pk2(acc[i][j][2] + bval, acc[i][j][3] + bval);
                *(uint2*)&T[(j * 16 + c) * 72 + i * 16 + q * 4] = pr;
            }
        }
        const size_t vtbase = ((size_t)(b * NHEADS + h)) * HDIM * SEQ + s0;
        #pragma unroll
        for (int ii = 0; ii < 8; ++ii) {
            int d = (l >> 3) + 8 * ii;
            int sch = (l & 7) * 8;
            uint4 vv = *(const uint4*)&T[d * 72 + sch];
            *(uint4*)&VT[vtbase + (size_t)d * SEQ + sch] = vv;
        }
    }
}

// ---------------------------------------------------------------------------
// Flash attention (R5/R7, best-measured 45.6us): 2x2 KEY/Q split, K+V in LDS
// staged depth-2, software pipeline (QK^T j+1 overlaps softmax+PV j), NBUF=3,
// x6 unroll, 768 blocks (3/CU).
// ---------------------------------------------------------------------------
__global__ __launch_bounds__(256, 3)
void attn_kernel(const u16* __restrict__ Qb, const u16* __restrict__ Kb,
                 const u16* __restrict__ VT, u16* __restrict__ AO)
{
    __shared__ __align__(16) u16 Ks[3][4096];   // [buf][64 keys x 64 d] swizzled
    __shared__ __align__(16) u16 Vs[3][4096];   // [buf][64 d x 64 keys] swizzled

    const int blk = blockIdx.x;
    const int g = blk & 7, kk = blk >> 3;       // g -> XCD (round-robin heuristic)
    const int bh = g * 3 + (kk >> 5);           // same-bh blocks share an XCD (KV L2 reuse)
    const int qt = kk & 31;

    const int tid = threadIdx.x;
    const int w = tid >> 6, l = tid & 63;
    const int c = l & 15, q = l >> 4;
    const int wq = w >> 1, wk = w & 1;          // q-half, key-half

    const u16* qg = Qb + ((size_t)bh * SEQ + qt * 64 + wq * 32) * HDIM;
    const u16* kg = Kb + ((size_t)bh * SEQ) * HDIM;
    const u16* vg = VT + ((size_t)bh * HDIM) * SEQ;

    // async staging geometry: wave w fills rows [w*16, w*16+16) of each tile.
    const int r8 = l >> 3, ch = l & 7;
    const int gch = ch ^ r8;                    // swizzle is an involution

    // Q^T B-fragments for this wave's 2 q-blocks (16 VGPR)
    bf16x8 bq[2][2];
    #pragma unroll
    for (int qb2 = 0; qb2 < 2; ++qb2) {
        bq[qb2][0] = *(const bf16x8*)&qg[(qb2 * 16 + c) * HDIM + q * 8];
        bq[qb2][1] = *(const bf16x8*)&qg[(qb2 * 16 + c) * HDIM + 32 + q * 8];
    }

    f32x4 o[4][2] = {};                 // [db][qb2] partial O^T over 32-key slice
    float lrow[2] = {0.f, 0.f};         // per-qb2 partial row sums

    const int NT = SEQ / 64;   // 32

#define STAGE(JT, BS) {                                                       \
    int row0 = w * 16 + r8;                                                   \
    async16(&kg[(size_t)((JT) * 64 + row0) * HDIM + gch * 8],                 \
            &Ks[BS][(w * 16) * 64 + l * 8]);                                  \
    async16(&vg[(size_t)row0 * SEQ + (JT) * 64 + gch * 8],                    \
            &Vs[BS][(w * 16) * 64 + l * 8]);                                  \
    async16(&kg[(size_t)((JT) * 64 + row0 + 8) * HDIM + gch * 8],             \
            &Ks[BS][(w * 16 + 8) * 64 + l * 8]);                              \
    async16(&vg[(size_t)(row0 + 8) * SEQ + (JT) * 64 + gch * 8],              \
            &Vs[BS][(w * 16 + 8) * 64 + l * 8]);                              \
}

    // S_slice^T[key][qrow]: A = 32 K rows (2 kb2), B = Q^T (2 qb2 blocks)
#define QKT(SN, BN) {                                                         \
    __builtin_amdgcn_s_setprio(1);                                            \
    _Pragma("unroll")                                                         \
    for (int kb2 = 0; kb2 < 2; ++kb2) {                                       \
        bf16x8 ak0 = *(const bf16x8*)&Ks[BN][(wk * 32 + kb2 * 16 + c) * 64 +  \
                                             (((q    ) ^ (c & 7)) << 3)];     \
        bf16x8 ak1 = *(const bf16x8*)&Ks[BN][(wk * 32 + kb2 * 16 + c) * 64 +  \
                                             (((q | 4) ^ (c & 7)) << 3)];     \
        _Pragma("unroll")                                                     \
        for (int qb2 = 0; qb2 < 2; ++qb2) {                                   \
            f32x4 zz = {};                                                    \
            zz = mfma32(ak0, bq[qb2][0], zz);                                 \
            SN[kb2][qb2] = mfma32(ak1, bq[qb2][1], zz);                       \
        }                                                                     \
    }                                                                         \
    __builtin_amdgcn_s_setprio(0);                                            \
}

    // exp2 softmax (log2e folded into Q), P->bf16 frags, O^T += V^T.P^T
#define SOFTPV(SC, BC) {                                                      \
    _Pragma("unroll")                                                         \
    for (int kb2 = 0; kb2 < 2; ++kb2)                                         \
        _Pragma("unroll")                                                     \
        for (int qb2 = 0; qb2 < 2; ++qb2) {                                   \
            float p0 = exp2_hw(SC[kb2][qb2][0]);                              \
            float p1 = exp2_hw(SC[kb2][qb2][1]);                              \
            float p2 = exp2_hw(SC[kb2][qb2][2]);                              \
            float p3 = exp2_hw(SC[kb2][qb2][3]);                              \
            SC[kb2][qb2][0] = p0; SC[kb2][qb2][1] = p1;                       \
            SC[kb2][qb2][2] = p2; SC[kb2][qb2][3] = p3;                       \
            lrow[qb2] += (p0 + p1) + (p2 + p3);                               \
        }                                                                     \
    bf16x4 bp[2][2];                                                          \
    _Pragma("unroll")                                                         \
    for (int kb2 = 0; kb2 < 2; ++kb2)                                         \
        _Pragma("unroll")                                                     \
        for (int qb2 = 0; qb2 < 2; ++qb2) {                                   \
            uint2 pr;                                                         \
            pr.x = pk2(SC[kb2][qb2][0], SC[kb2][qb2][1]);                     \
            pr.y = pk2(SC[kb2][qb2][2], SC[kb2][qb2][3]);                     \
            bp[kb2][qb2] = __builtin_bit_cast(bf16x4, pr);                    \
        }                                                                     \
    __builtin_amdgcn_s_setprio(1);                                            \
    _Pragma("unroll")                                                         \
    for (int db = 0; db < 4; ++db) {                                          \
        bf16x4 av0 = *(const bf16x4*)&Vs[BC][(db * 16 + c) * 64 +             \
                  (((4 * wk     + (q >> 1)) ^ (c & 7)) << 3) + ((q & 1) << 2)]; \
        bf16x4 av1 = *(const bf16x4*)&Vs[BC][(db * 16 + c) * 64 +             \
                  (((4 * wk + 2 + (q >> 1)) ^ (c & 7)) << 3) + ((q & 1) << 2)]; \
        _Pragma("unroll")                                                     \
        for (int qb2 = 0; qb2 < 2; ++qb2) {                                   \
            o[db][qb2] = mfma16(av0, bp[0][qb2], o[db][qb2]);                 \
            o[db][qb2] = mfma16(av1, bp[1][qb2], o[db][qb2]);                 \
        }                                                                     \
    }                                                                         \
    __builtin_amdgcn_s_setprio(0);                                            \
}

#define BODY(J, SC, SN, BC, BN, BS) {                                         \
    asm volatile("s_waitcnt vmcnt(0)" ::: "memory");                          \
    __builtin_amdgcn_s_barrier();                                             \
    if ((J) + 2 < NT) STAGE((J) + 2, BS);                                     \
    if ((J) + 1 < NT) QKT(SN, BN);                                            \
    SOFTPV(SC, BC);                                                           \
}

    f32x4 scA[2][2], scB[2][2];

    // prologue: stage tiles 0,1; compute QK^T(0)
    STAGE(0, 0);
    STAGE(1, 1);
    asm volatile("s_waitcnt vmcnt(4)" ::: "memory");   // tile 0 landed
    __builtin_amdgcn_s_barrier();
    QKT(scA, 0);

    // main: 30 bodies; all buffer/S indices compile-time (x6 unroll)
    for (int jb = 0; jb < 30; jb += 6) {
        BODY(jb + 0, scA, scB, 0, 1, 2);
        BODY(jb + 1, scB, scA, 1, 2, 0);
        BODY(jb + 2, scA, scB, 2, 0, 1);
        BODY(jb + 3, scB, scA, 0, 1, 2);
        BODY(jb + 4, scA, scB, 1, 2, 0);
        BODY(jb + 5, scB, scA, 2, 0, 1);
    }
    // tail: j=30 (stage guard off, computes QK^T(31)), then j=31 (no next)
    BODY(30, scA, scB, 0, 1, 2);
    SOFTPV(scB, 1);                      // j=31: V[31] in buf 31%3==1, landed

#undef STAGE
#undef QKT
#undef SOFTPV
#undef BODY

    // ---- cross-wave reduction: wk-pairs combine 32-key partials ----
    #pragma unroll
    for (int qb2 = 0; qb2 < 2; ++qb2) {
        lrow[qb2] += __shfl_xor(lrow[qb2], 16);
        lrow[qb2] += __shfl_xor(lrow[qb2], 32);
    }

    __syncthreads();                     // all tile LDS reads done; reuse smem
    float* SCR = (float*)&Ks[0][0];      // 16KB O exchange + 256B row sums
    float* LR  = SCR + 4096;

    if (wk == 1) {                       // push partials
        #pragma unroll
        for (int db = 0; db < 4; ++db)
            #pragma unroll
            for (int qb2 = 0; qb2 < 2; ++qb2)
                *(f32x4*)&SCR[((wq * 8 + db * 2 + qb2) << 8) + l * 4] = o[db][qb2];
        if (q == 0) {
            LR[(wq * 2 + 0) * 16 + c] = lrow[0];
            LR[(wq * 2 + 1) * 16 + c] = lrow[1];
        }
    }
    __syncthreads();

    if (wk == 0) {                       // add partner, normalize, write
        float inv[2];
        #pragma unroll
        for (int qb2 = 0; qb2 < 2; ++qb2)
            inv[qb2] = 1.0f / (lrow[qb2] + LR[(wq * 2 + qb2) * 16 + c]);
        const int b = bh / NHEADS, h = bh % NHEADS;
        #pragma unroll
        for (int qb2 = 0; qb2 < 2; ++qb2) {
            const int s = qt * 64 + wq * 32 + qb2 * 16 + c;
            u16* ao = AO + ((size_t)(b * SEQ + s)) * EMBED + h * HDIM;
            #pragma unroll
            for (int db = 0; db < 4; ++db) {
                f32x4 part = *(const f32x4*)&SCR[((wq * 8 + db * 2 + qb2) << 8) + l * 4];
                f32x4 t = o[db][qb2] + part;
                uint2 oo;
                oo.x = pk2(t[0] * inv[qb2], t[1] * inv[qb2]);
                oo.y = pk2(t[2] * inv[qb2], t[3] * inv[qb2]);
                *(uint2*)&ao[db * 16 + q * 4] = oo;
            }
        }
    }
}

// ---------------------------------------------------------------------------
// Output projection (R7, best-measured): 64x64 tile, BK=32 -> grid (64,12)
// = 768 blocks = exactly 3/CU balanced. LDS 16KB. async16-after-barrier
// pipeline + (row>>1)&3 chunk swizzle.
// ---------------------------------------------------------------------------
__global__ __launch_bounds__(256)
void out_gemm(const u16* __restrict__ A, const u16* __restrict__ W,
              const float* __restrict__ bias, float* __restrict__ out)
{
    __shared__ __align__(16) u16 As[2][2048];   // [buf][64 rows x 32 cols] swizzled
    __shared__ __align__(16) u16 Bs[2][2048];
    const int m0 = blockIdx.x * 64;
    const int n0 = blockIdx.y * 64;
    const int tid = threadIdx.x;
    const int w = tid >> 6, l = tid & 63;
    const int c = l & 15, q = l >> 4;
    const int sr = l >> 2;
    const int gch2 = (l & 3) ^ ((l >> 3) & 3);  // (row>>1)&3 involution swizzle

    // stage K-tile 0: wave w covers rows w*16..+15 (1 async16 per operand)
    {
        int row = w * 16 + sr;
        async16(&A[(size_t)(m0 + row) * EMBED + gch2 * 8], &As[0][(w * 16) * 32 + l * 8]);
        async16(&W[(size_t)(n0 + row) * EMBED + gch2 * 8], &Bs[0][(w * 16) * 32 + l * 8]);
    }

    f32x4 acc[4] = {};
    const int NK = EMBED / 32;   // 24

    #pragma unroll 2
    for (int kt = 0; kt < NK; ++kt) {
        const int cur = kt & 1;
        __syncthreads();
        if (kt + 1 < NK) {
            int k0 = (kt + 1) * 32;
            int row = w * 16 + sr;
            async16(&A[(size_t)(m0 + row) * EMBED + k0 + gch2 * 8],
                    &As[cur ^ 1][(w * 16) * 32 + l * 8]);
            async16(&W[(size_t)(n0 + row) * EMBED + k0 + gch2 * 8],
                    &Bs[cur ^ 1][(w * 16) * 32 + l * 8]);
        }
        const int cs = (q ^ ((c >> 1) & 3)) << 3;
        bf16x8 af = *(const bf16x8*)&As[cur][(w * 16 + c) * 32 + cs];
        bf16x8 bfr[4];
        #pragma unroll
        for (int j = 0; j < 4; ++j)
            bfr[j] = *(const bf16x8*)&Bs[cur][(j * 16 + c) * 32 + cs];
        #pragma unroll
        for (int j = 0; j < 4; ++j)
            acc[j] = mfma32(af, bfr[j], acc[j]);
    }

    #pragma unroll
    for (int j = 0; j < 4; ++j) {
        int n = n0 + j * 16 + c;
        float bval = bias[n];
        #pragma unroll
        for (int r = 0; r < 4; ++r) {
            int m = m0 + w * 16 + q * 4 + r;
            out[(size_t)m * EMBED + n] = acc[j][r] + bval;
        }
    }
}

// ---------------------------------------------------------------------------
extern "C" void kernel_launch(void* const* d_in, const int* in_sizes, int n_in,
                              void* d_out, int out_size, void* d_ws, size_t ws_size,
                              hipStream_t stream)
{
    const float* x    = (const float*)d_in[0];
    const float* wqkv = (const float*)d_in[1];
    const float* bqkv = (const float*)d_in[2];
    const float* wout = (const float*)d_in[3];
    const float* bout = (const float*)d_in[4];
    float* out = (float*)d_out;

    const int nx  = NTOK * EMBED;         // 3,145,728
    const int nwq = QKV_N * EMBED;        // 1,769,472
    const int nwo = EMBED * EMBED;        //   589,824
    const size_t per = (size_t)NBATCH * NHEADS * SEQ * HDIM;  // 3,145,728

    u16* xb    = (u16*)d_ws;
    u16* wqkvb = xb + nx;
    u16* woutb = wqkvb + nwq;
    u16* Qb    = woutb + nwo;
    u16* Kb    = Qb + per;
    u16* VT    = Kb + per;
    u16* AO    = VT + per;   // [token][EMBED] bf16, written directly by attn

    int castTot = (nx + nwq + nwo) / 4;
    cast_kernel<<<castTot / 256, 256, 0, stream>>>(x, xb, nx, wqkv, wqkvb, nwq, wout, woutb, nwo);

    dim3 g1(NTOK / 128, QKV_N / 128);     // (32, 18)
    qkv_gemm<<<g1, 256, 0, stream>>>(xb, wqkvb, bqkv, Qb, Kb, VT);

    attn_kernel<<<BHTOT * 32, 256, 0, stream>>>(Qb, Kb, VT, AO);   // 768 blocks

    dim3 g3(NTOK / 64, EMBED / 64);       // (64, 12) = 768 blocks, 3/CU balanced
    out_gemm<<<g3, 256, 0, stream>>>(AO, woutb, bout, out);
}